// Round 5
// baseline (352.611 us; speedup 1.0000x reference)
//
#include <hip/hip_runtime.h>

// Problem constants
#define B_TOT 65536
#define WS_P1W 4096                 // permuted bf16 p1W: 48*512*2 = 49152 B
#define WS_EV  (1u << 20)           // per-batch blocks: 512B E + 1024B V = 1536 B * 65536
#define EV_BYTES 100663296u         // 65536 * 1536
#define WS_PART (WS_EV + EV_BYTES)  // per-block D partials: 2048 * 256 * 4 = 2 MB

typedef float f32x4 __attribute__((ext_vector_type(4)));
typedef short s16x8 __attribute__((ext_vector_type(8)));

__device__ __forceinline__ float bf2f(unsigned short h) {
    unsigned u = ((unsigned)h) << 16;
    return __builtin_bit_cast(float, u);
}
// cheap bf16 pair pack: round-half-up (add 0x8000) + v_perm_b32 high-half merge.
__device__ __forceinline__ unsigned pack2(float a, float b) {
    unsigned ua = __builtin_bit_cast(unsigned, a) + 0x8000u;
    unsigned ub = __builtin_bit_cast(unsigned, b) + 0x8000u;
    return __builtin_amdgcn_perm(ub, ua, 0x07060302u);  // lo16=a, hi16=b
}
__device__ __forceinline__ unsigned short f2bf(float f) {
    return (unsigned short)((__builtin_bit_cast(unsigned, f) + 0x8000u) >> 16);
}
__device__ __forceinline__ s16x8 cvt8(float4 a, float4 b) {
    uint4 u;
    u.x = pack2(a.x, a.y); u.y = pack2(a.z, a.w);
    u.z = pack2(b.x, b.y); u.w = pack2(b.z, b.w);
    return __builtin_bit_cast(s16x8, u);
}
#define MFMA(a, b, c) __builtin_amdgcn_mfma_f32_16x16x32_bf16((a), (b), (c), 0, 0, 0)

// ---------------------------------------------------------------------------
// k1: per-batch Q,K,V linears (bf16 MFMA), deferred normalization (R3),
// TWO-BATCH INTERLEAVE: each outer iteration runs two independent batch
// chains (loads, linears, LDS transpose round-trip, S-MFMA, norm shuffles,
// exp) so the wave always has a second chain to issue while one is stalled.
// R3 established k1 is latency-chain-bound (VALU cut 33->25% busy, VGPR
// 68->52, time flat).  Scalar post-add biases keep VGPR in range.
// Launched as TWO 1024-block dispatches (blkoff) so k2/k1b surface in the
// rocprof top-5 (k1 was hiding them all).  D region zeroed by dispatch 0
// block 0; per-block D partials stored plain+coalesced for k1b.
// ---------------------------------------------------------------------------
__global__ __launch_bounds__(256) void k1_stats(
    const float* __restrict__ e1, const float* __restrict__ e2,
    const float* __restrict__ qW, const float* __restrict__ qb,
    const float* __restrict__ kW, const float* __restrict__ kb,
    const float* __restrict__ vW, const float* __restrict__ vb,
    char* __restrict__ ws, int blkoff) {

    const int tid = threadIdx.x;
    const int lane = tid & 63;
    const int widx = tid >> 6;
    const int col = lane & 15;      // n-index (e_lo / d) in MFMA layouts
    const int quad = lane >> 4;

    // [wave][Q/K][batch-parity][16 rows x 40 shorts padded] = 20 KiB
    __shared__ __align__(16) unsigned short qk_lds[4][2][2][16 * 40];
    __shared__ float Dblk[256];
    if (blkoff == 0 && blockIdx.x == 0) ((float*)ws)[tid] = 0.f;  // zero D
    Dblk[tid] = 0.f;
    __syncthreads();

    // Weight B-fragments: B_h[k=l][n=e_lo] = W[e_lo+16h][l], lane holds 8 consecutive l.
    s16x8 wq[2], wk[2], wv[2];
    float bq[2], bk[2], bv[2];      // scalar post-add biases (per-lane row = col+16h)
#pragma unroll
    for (int h = 0; h < 2; ++h) {
        int row = col + 16 * h;
        const float4* pq = (const float4*)(qW + row * 32 + quad * 8);
        const float4* pk = (const float4*)(kW + row * 32 + quad * 8);
        const float4* pv = (const float4*)(vW + row * 32 + quad * 8);
        wq[h] = cvt8(pq[0], pq[1]);
        wk[h] = cvt8(pk[0], pk[1]);
        wv[h] = cvt8(pv[0], pv[1]);
        bq[h] = qb[row]; bk[h] = kb[row]; bv[h] = vb[row];
    }

    float dacc[4] = {0.f, 0.f, 0.f, 0.f};
    char* evbase = ws + WS_EV;
    const f32x4 z = {0.f, 0.f, 0.f, 0.f};

    const int gw = (blkoff + blockIdx.x) * 4 + widx;
    for (int i = 0; i < 4; ++i) {
        // ---- load + convert both batches (8 concurrent float4 loads) ----
        s16x8 fx1[2], fx2[2];
#pragma unroll
        for (int p = 0; p < 2; ++p) {
            const int b = gw * 8 + i * 2 + p;
            const float4* x1p = (const float4*)(e1 + (size_t)b * 512 + col * 32 + quad * 8);
            const float4* x2p = (const float4*)(e2 + (size_t)b * 512 + col * 32 + quad * 8);
            float4 a0 = x1p[0], a1 = x1p[1];
            float4 b0 = x2p[0], b1 = x2p[1];
            fx1[p] = cvt8(a0, a1);
            fx2[p] = cvt8(b0, b1);
        }
        // ---- linears + products + LDS stage + V store, both batches ----
#pragma unroll
        for (int p = 0; p < 2; ++p) {
            const int b = gw * 8 + i * 2 + p;
            char* bbase = evbase + (size_t)b * 1536;
            {   // Q -> LDS (C/D layout: value (h,r) = M[row=quad*4+r][e=col+16h];
                // rows store permuted e' = e_lo*2 + h, shared by Q,K)
                f32x4 qa = MFMA(fx1[p], wq[0], z), qc = MFMA(fx2[p], wq[0], z);
                f32x4 qd = MFMA(fx1[p], wq[1], z), qe = MFMA(fx2[p], wq[1], z);
                unsigned* dst = (unsigned*)qk_lds[widx][0][p];
#pragma unroll
                for (int r = 0; r < 4; ++r)
                    dst[(quad * 4 + r) * 20 + col] =
                        pack2((qa[r] + bq[0]) * (qc[r] + bq[0]),
                              (qd[r] + bq[1]) * (qe[r] + bq[1]));
            }
            {   // K -> LDS
                f32x4 ka = MFMA(fx1[p], wk[0], z), kc = MFMA(fx2[p], wk[0], z);
                f32x4 kd = MFMA(fx1[p], wk[1], z), ke = MFMA(fx2[p], wk[1], z);
                unsigned* dst = (unsigned*)qk_lds[widx][1][p];
#pragma unroll
                for (int r = 0; r < 4; ++r)
                    dst[(quad * 4 + r) * 20 + col] =
                        pack2((ka[r] + bk[0]) * (kc[r] + bk[0]),
                              (kd[r] + bk[1]) * (ke[r] + bk[1]));
            }
            {   // V -> global, blocked for k2 B-frags: block(h, e_lo=col, c-half quad>>1)
                f32x4 va = MFMA(fx1[p], wv[0], z), vc = MFMA(fx2[p], wv[0], z);
                f32x4 vd = MFMA(fx1[p], wv[1], z), ve = MFMA(fx2[p], wv[1], z);
                uint2 vst0, vst1;
                vst0.x = pack2((va[0] + bv[0]) * (vc[0] + bv[0]),
                               (va[1] + bv[0]) * (vc[1] + bv[0]));
                vst0.y = pack2((va[2] + bv[0]) * (vc[2] + bv[0]),
                               (va[3] + bv[0]) * (vc[3] + bv[0]));
                vst1.x = pack2((vd[0] + bv[1]) * (ve[0] + bv[1]),
                               (vd[1] + bv[1]) * (ve[1] + bv[1]));
                vst1.y = pack2((vd[2] + bv[1]) * (ve[2] + bv[1]),
                               (vd[3] + bv[1]) * (ve[3] + bv[1]));
                *(uint2*)(bbase + 512 + ((0 * 16 + col) * 2 + (quad >> 1)) * 16 + (quad & 1) * 8) = vst0;
                *(uint2*)(bbase + 512 + ((1 * 16 + col) * 2 + (quad >> 1)) * 16 + (quad & 1) * 8) = vst1;
            }
        }
        // ---- read back raw Q/K, S-MFMA + deferred norms + exp, both batches ----
#pragma unroll
        for (int p = 0; p < 2; ++p) {
            const int b = gw * 8 + i * 2 + p;
            char* bbase = evbase + (size_t)b * 1536;
            const unsigned short* qbuf = qk_lds[widx][0][p];
            const unsigned short* kbuf = qk_lds[widx][1][p];
            s16x8 aq  = *(const s16x8*)(qbuf + col * 40 + quad * 8);
            s16x8 bk8 = *(const s16x8*)(kbuf + col * 40 + quad * 8);
            f32x4 S = MFMA(aq, bk8, z);   // S_raw[c=quad*4+r][d=col]

            float ssq = 0.f, ssk = 0.f;
#pragma unroll
            for (int j = 0; j < 8; ++j) {
                float qf = bf2f((unsigned short)aq[j]);  ssq += qf * qf;
                float kf = bf2f((unsigned short)bk8[j]); ssk += kf * kf;
            }
            ssq += __shfl_xor(ssq, 16); ssq += __shfl_xor(ssq, 32);
            ssk += __shfl_xor(ssk, 16); ssk += __shfl_xor(ssk, 32);
            float invq = 1.f / fmaxf(sqrtf(ssq), 1e-12f);   // at lane: row c = col
            float invk = 1.f / fmaxf(sqrtf(ssk), 1e-12f);   // at lane: row d = col
            float iq0 = __shfl(invq, quad * 4 + 0);
            float iq1 = __shfl(invq, quad * 4 + 1);
            float iq2 = __shfl(invq, quad * 4 + 2);
            float iq3 = __shfl(invq, quad * 4 + 3);

            float ex0 = __expf(S[0] * (iq0 * invk));
            float ex1 = __expf(S[1] * (iq1 * invk));
            float ex2 = __expf(S[2] * (iq2 * invk));
            float ex3 = __expf(S[3] * (iq3 * invk));
            dacc[0] += ex0; dacc[1] += ex1; dacc[2] += ex2; dacc[3] += ex3;
            uint2 est; est.x = pack2(ex0, ex1); est.y = pack2(ex2, ex3);
            *(uint2*)(bbase + col * 32 + quad * 8) = est;   // E [d][c] bf16
        }
    }
    // Denominator: regs -> block LDS (atomics, conflict-free) -> coalesced store
#pragma unroll
    for (int r = 0; r < 4; ++r)
        atomicAdd(&Dblk[col * 16 + quad * 4 + r], dacc[r]);
    __syncthreads();
    ((float*)(ws + WS_PART))[(size_t)(blkoff + blockIdx.x) * 256 + tid] = Dblk[tid];
}

// ---------------------------------------------------------------------------
// k1b: 96 blocks.  All blocks: build bf16 p1W permuted into k2's i' order.
// Blocks 0..15 additionally reduce the 2048x256 partials COALESCED (block g
// streams rows g*128..+127, threads cover the 256 columns contiguously) and
// atomicAdd into D[256] at ws[0..1KB).  Reciprocal moved to k2.
// ---------------------------------------------------------------------------
__global__ __launch_bounds__(256) void k1b_prep(const float* __restrict__ p1W,
                                                char* __restrict__ ws) {
    const int t = threadIdx.x;
    const int g = blockIdx.x;
    const int idx = g * 256 + t;                 // 96*256 = 24576
    {
        int jj   = idx & 7;
        int lane = (idx >> 3) & 63;
        int ktnt = idx >> 9;
        int kt = ktnt & 15, nt = ktnt >> 4;
        int n_lo = lane & 15, q8 = lane >> 4;
        int j2  = nt * 16 + n_lo;                // output neuron [0,48)
        int ip  = kt * 32 + q8 * 8 + jj;         // i' in [0,512)
        int e_lo = ip >> 5, qq = (ip >> 3) & 3, hh = (ip >> 2) & 1, r = ip & 3;
        int orig = (qq * 4 + r) * 32 + (e_lo + 16 * hh);
        ((unsigned short*)(ws + WS_P1W))[idx] = f2bf(p1W[j2 * 512 + orig]);
    }
    if (g < 16) {
        const float* part = (const float*)(ws + WS_PART);
        float s = 0.f;
        for (int r = 0; r < 128; ++r)
            s += part[(size_t)(g * 128 + r) * 256 + t];   // coalesced 1KB rows
        atomicAdd(((float*)ws) + t, s);          // 16 blocks x 256 atomics
    }
}

// ---------------------------------------------------------------------------
// k2: cooperative 4-wave block over ONE 16-batch group.  Phase1 (prefetched
// E/V loads): each wave computes 4 of the 16 per-batch out[d][e] rows into a
// shared 16KB H (bf16, XOR-swizzled chunks).  Phase2 (prefetched weights):
// each wave takes 4 of the 16 k-tiles of MLP1 (MFMA), partial accs reduced
// through LDS (aliased over H).  Phase3: ALL FOUR waves.  dinv computed
// locally (1/D, 8 divides per thread — D finalized by k1b).
// ---------------------------------------------------------------------------
__global__ __launch_bounds__(256) void k2_apply(
    const char* __restrict__ ws, const float* __restrict__ p1b,
    const float* __restrict__ p2W, const float* __restrict__ p2b,
    float* __restrict__ out) {

    const int tid = threadIdx.x;
    const int lane = tid & 63;
    const int widx = tid >> 6;
    const int col = lane & 15;
    const int quad = lane >> 4;
    const int qm = quad & 1;        // mirrored address for upper quads

    __shared__ __align__(16) unsigned short Hs[16 * 512];   // 16 KiB
    float* P = (float*)Hs;          // aliased partial-sum buffer (12 KiB <= 16 KiB)

    // Hoisted tail constants — issued first, latency hidden under phases 1-2
    float p1bias[3], p2w[3][3];
#pragma unroll
    for (int nt = 0; nt < 3; ++nt) {
        p1bias[nt] = p1b[col + 16 * nt];
#pragma unroll
        for (int t2 = 0; t2 < 3; ++t2) p2w[nt][t2] = p2W[t2 * 48 + col + 16 * nt];
    }
    const float pb0 = p2b[0], pb1 = p2b[1], pb2 = p2b[2];

    // 1/denominator from D (k1b atomic-finalized), vector-loaded
    const float* Dws = (const float*)ws;
    const float4 dva = *(const float4*)(Dws + col * 16 + qm * 8);
    const float4 dvb = *(const float4*)(Dws + col * 16 + qm * 8 + 4);
    float dinv[8] = {1.f / dva.x, 1.f / dva.y, 1.f / dva.z, 1.f / dva.w,
                     1.f / dvb.x, 1.f / dvb.y, 1.f / dvb.z, 1.f / dvb.w};

    const char* evbase = ws + WS_EV;
    const unsigned short* p1wp = (const unsigned short*)(ws + WS_P1W);
    const int g = blockIdx.x;
    const f32x4 z = {0.f, 0.f, 0.f, 0.f};
    const s16x8 zz = {0, 0, 0, 0, 0, 0, 0, 0};

    // Phase 1: out[d][e] for batches i = widx*4 .. +3 -> H rows (bf16, swizzled)
    {
        const char* bb0 = evbase + (size_t)(g * 16 + widx * 4) * 1536;
        const int eoff  = col * 32 + qm * 16;
        const int voff0 = 512 + (col * 2 + qm) * 16;
        const int voff1 = 512 + ((16 + col) * 2 + qm) * 16;
        s16x8 ne  = *(const s16x8*)(bb0 + eoff);
        s16x8 nv0 = *(const s16x8*)(bb0 + voff0);
        s16x8 nv1 = *(const s16x8*)(bb0 + voff1);
#pragma unroll
        for (int ii = 0; ii < 4; ++ii) {
            s16x8 eraw = ne, bf0 = nv0, bf1 = nv1;
            if (ii < 3) {
                const char* nb = bb0 + (size_t)(ii + 1) * 1536;
                ne  = *(const s16x8*)(nb + eoff);
                nv0 = *(const s16x8*)(nb + voff0);
                nv1 = *(const s16x8*)(nb + voff1);
            }
            float ef[8];
#pragma unroll
            for (int j = 0; j < 8; ++j)
                ef[j] = bf2f((unsigned short)eraw[j]) * dinv[j];
            uint4 ua;
            ua.x = pack2(ef[0], ef[1]); ua.y = pack2(ef[2], ef[3]);
            ua.z = pack2(ef[4], ef[5]); ua.w = pack2(ef[6], ef[7]);
            s16x8 afrag = __builtin_bit_cast(s16x8, ua);
            if (quad >= 2) { afrag = zz; bf0 = zz; bf1 = zz; }  // K-padding (c>=16 -> 0)
            f32x4 o0 = MFMA(afrag, bf0, z);   // out[d=quad*4+r][e=col]
            f32x4 o1 = MFMA(afrag, bf1, z);   // out[d=quad*4+r][e=col+16]
            uint4 uh;
            uh.x = pack2(o0[0], o0[1]); uh.y = pack2(o0[2], o0[3]);
            uh.z = pack2(o1[0], o1[1]); uh.w = pack2(o1[2], o1[3]);
            const int i = widx * 4 + ii;
            int chunk = (col * 4 + quad) ^ (i & 7);   // 16B-chunk XOR swizzle
            *(uint4*)(Hs + i * 512 + chunk * 8) = uh;
        }
    }
    __syncthreads();

    // Phase 2: MLP1 — H[16 x 512] @ p1Wp^T, wave widx handles kt = widx*4..+3
    f32x4 acc[3] = {z, z, z};
    {
        const int kt0 = widx * 4;
        s16x8 nw0 = *(const s16x8*)(p1wp + ((0 * 16 + kt0) * 64 + lane) * 8);
        s16x8 nw1 = *(const s16x8*)(p1wp + ((1 * 16 + kt0) * 64 + lane) * 8);
        s16x8 nw2 = *(const s16x8*)(p1wp + ((2 * 16 + kt0) * 64 + lane) * 8);
#pragma unroll
        for (int t2 = 0; t2 < 4; ++t2) {
            const int kt = widx * 4 + t2;
            s16x8 w0 = nw0, w1 = nw1, w2 = nw2;
            if (t2 < 3) {
                nw0 = *(const s16x8*)(p1wp + ((0 * 16 + kt + 1) * 64 + lane) * 8);
                nw1 = *(const s16x8*)(p1wp + ((1 * 16 + kt + 1) * 64 + lane) * 8);
                nw2 = *(const s16x8*)(p1wp + ((2 * 16 + kt + 1) * 64 + lane) * 8);
            }
            int chunk = (kt * 4 + quad) ^ (col & 7);
            s16x8 a = *(const s16x8*)(Hs + col * 512 + chunk * 8);
            acc[0] = MFMA(a, w0, acc[0]);
            acc[1] = MFMA(a, w1, acc[1]);
            acc[2] = MFMA(a, w2, acc[2]);
        }
    }
    __syncthreads();   // H reads done before P overwrites it

    // partials -> LDS: P[widx][lane][nt*4+r], lane stride 12 floats (48B)
#pragma unroll
    for (int nt = 0; nt < 3; ++nt)
        *(f32x4*)(P + (widx * 64 + lane) * 12 + nt * 4) = acc[nt];
    __syncthreads();

    // Phase 3: all 4 waves — wave widx handles r = widx (batches quad*4+widx)
    {
        float s3[3] = {0.f, 0.f, 0.f};
#pragma unroll
        for (int w = 0; w < 4; ++w)
#pragma unroll
            for (int nt = 0; nt < 3; ++nt)
                s3[nt] += P[(w * 64 + lane) * 12 + nt * 4 + widx];
        float pp[3] = {0.f, 0.f, 0.f};
#pragma unroll
        for (int nt = 0; nt < 3; ++nt) {
            float hv = fmaxf(s3[nt] + p1bias[nt], 0.f);
            pp[0] += hv * p2w[nt][0];
            pp[1] += hv * p2w[nt][1];
            pp[2] += hv * p2w[nt][2];
        }
#pragma unroll
        for (int m = 1; m <= 8; m <<= 1) {
            pp[0] += __shfl_xor(pp[0], m);
            pp[1] += __shfl_xor(pp[1], m);
            pp[2] += __shfl_xor(pp[2], m);
        }
        float h0 = pp[0] + pb0, h1 = pp[1] + pb1, h2 = pp[2] + pb2;
        float inv = 1.f / fmaxf(sqrtf(h0 * h0 + h1 * h1 + h2 * h2), 1e-12f);
        if (col < 3) {
            float v = (col == 0) ? h0 : ((col == 1) ? h1 : h2);
            out[(size_t)(g * 16 + quad * 4 + widx) * 3 + col] = v * inv;
        }
    }
}

// ---------------------------------------------------------------------------
extern "C" void kernel_launch(void* const* d_in, const int* in_sizes, int n_in,
                              void* d_out, int out_size, void* d_ws, size_t ws_size,
                              hipStream_t stream) {
    const float* e1  = (const float*)d_in[0];
    const float* e2  = (const float*)d_in[1];
    const float* qW  = (const float*)d_in[2];
    const float* qb  = (const float*)d_in[3];
    const float* kW  = (const float*)d_in[4];
    const float* kb  = (const float*)d_in[5];
    const float* vW  = (const float*)d_in[6];
    const float* vb  = (const float*)d_in[7];
    const float* p1W = (const float*)d_in[8];
    const float* p1b = (const float*)d_in[9];
    const float* p2W = (const float*)d_in[10];
    const float* p2b = (const float*)d_in[11];
    float* out = (float*)d_out;
    char* ws = (char*)d_ws;

    k1_stats<<<1024, 256, 0, stream>>>(e1, e2, qW, qb, kW, kb, vW, vb, ws, 0);
    k1_stats<<<1024, 256, 0, stream>>>(e1, e2, qW, qb, kW, kb, vW, vb, ws, 1024);
    k1b_prep<<<96, 256, 0, stream>>>(p1W, ws);
    k2_apply<<<4096, 256, 0, stream>>>(ws, p1b, p2W, p2b, out);
}